// Round 1
// baseline (47.951 us; speedup 1.0000x reference)
//
#include <hip/hip_runtime.h>

// Covariance from (scales, quaternion) — 3D Gaussian splatting head.
// out[n] = upper-tri(R diag(s^2) R^T) with R from normalized quat.
// Memory-bound: 52 B/row traffic. 2 rows/thread for aligned vector I/O.

__device__ __forceinline__ void cov6(float r, float x, float y, float z,
                                     float s0, float s1, float s2,
                                     float* __restrict__ o) {
    float inv = rsqrtf(r * r + x * x + y * y + z * z);
    r *= inv; x *= inv; y *= inv; z *= inv;
    float R00 = 1.f - 2.f * (y * y + z * z);
    float R01 = 2.f * (x * y - r * z);
    float R02 = 2.f * (x * z + r * y);
    float R10 = 2.f * (x * y + r * z);
    float R11 = 1.f - 2.f * (x * x + z * z);
    float R12 = 2.f * (y * z - r * x);
    float R20 = 2.f * (x * z - r * y);
    float R21 = 2.f * (y * z + r * x);
    float R22 = 1.f - 2.f * (x * x + y * y);
    float a = s0 * s0, b = s1 * s1, c = s2 * s2;
    o[0] = R00 * R00 * a + R01 * R01 * b + R02 * R02 * c;  // cov00
    o[1] = R00 * R10 * a + R01 * R11 * b + R02 * R12 * c;  // cov01
    o[2] = R00 * R20 * a + R01 * R21 * b + R02 * R22 * c;  // cov02
    o[3] = R10 * R10 * a + R11 * R11 * b + R12 * R12 * c;  // cov11
    o[4] = R10 * R20 * a + R11 * R21 * b + R12 * R22 * c;  // cov12
    o[5] = R20 * R20 * a + R21 * R21 * b + R22 * R22 * c;  // cov22
}

__global__ __launch_bounds__(256) void gaus_cov_kernel(
    const float* __restrict__ scales,  // (N,3)
    const float* __restrict__ rots,    // (N,4)
    float* __restrict__ out,           // (N,6)
    int n, int npairs) {
    int t = blockIdx.x * blockDim.x + threadIdx.x;
    if (t >= npairs) return;
    long long row = 2ll * t;
    if (row + 1 < n) {
        // Fast path: 2 rows, fully vectorized & aligned.
        const float2* sp = reinterpret_cast<const float2*>(scales + 6ll * t);
        float2 sA = sp[0], sB = sp[1], sC = sp[2];
        const float4* rp = reinterpret_cast<const float4*>(rots + 8ll * t);
        float4 q0 = rp[0], q1 = rp[1];
        float o[12];
        cov6(q0.x, q0.y, q0.z, q0.w, sA.x, sA.y, sB.x, o);
        cov6(q1.x, q1.y, q1.z, q1.w, sB.y, sC.x, sC.y, o + 6);
        float4* op = reinterpret_cast<float4*>(out + 12ll * t);
        op[0] = make_float4(o[0], o[1], o[2], o[3]);
        op[1] = make_float4(o[4], o[5], o[6], o[7]);
        op[2] = make_float4(o[8], o[9], o[10], o[11]);
    } else if (row < n) {
        // Tail (only if n is odd): scalar path for the last row.
        float s0 = scales[3ll * row + 0];
        float s1 = scales[3ll * row + 1];
        float s2 = scales[3ll * row + 2];
        const float4* rp = reinterpret_cast<const float4*>(rots + 4ll * row);
        float4 q = rp[0];
        float o[6];
        cov6(q.x, q.y, q.z, q.w, s0, s1, s2, o);
        float* op = out + 6ll * row;
        op[0] = o[0]; op[1] = o[1]; op[2] = o[2];
        op[3] = o[3]; op[4] = o[4]; op[5] = o[5];
    }
}

extern "C" void kernel_launch(void* const* d_in, const int* in_sizes, int n_in,
                              void* d_out, int out_size, void* d_ws, size_t ws_size,
                              hipStream_t stream) {
    const float* scales = (const float*)d_in[0];
    const float* rots   = (const float*)d_in[1];
    float* out = (float*)d_out;
    int n = in_sizes[0] / 3;           // N rows
    int npairs = (n + 1) / 2;
    int block = 256;
    int grid = (npairs + block - 1) / block;
    gaus_cov_kernel<<<grid, block, 0, stream>>>(scales, rots, out, n, npairs);
}